// Round 3
// baseline (1255.412 us; speedup 1.0000x reference)
//
#include <hip/hip_runtime.h>
#include <hip/hip_bf16.h>

// VQDistortionLoss: fused cdist -> softmax -> soft-recon -> masked MSE.
// R3: RT=32 (2 row-tiles/block), dedup'd softmax (8 rows/wave, 4 codes/lane),
//     defer-max (T13), b128 score frags, recon B-frags from pre-transposed
//     global codebook cbT (kills the 4-way-conflicted tr-reads = 55% of R2's
//     LDS time), stage(i+1) overlapped with softmax(i), 3 barriers/ktile.

#define BB 8
#define DD 512
#define TT 4096
#define KKK 4096
#define ENC_STRIDE 320
#define KT 32
#define NWAVE 4

typedef __attribute__((ext_vector_type(8))) short bf16x8;  // 8 bf16 = 4 VGPR
typedef __attribute__((ext_vector_type(4))) float f32x4;

union FragU { bf16x8 v; uint2 h2[2]; ushort us[8]; unsigned long long q[2]; uint4 u4; };

// f32 -> bf16 RNE
static __device__ __forceinline__ ushort f2bf(float x) {
  unsigned u = __float_as_uint(x);
  unsigned r = (u + 0x7FFFu + ((u >> 16) & 1u)) >> 16;
  return (ushort)r;
}
static __device__ __forceinline__ uint2 f4tobf(float4 v) {
  uint2 r;
  r.x = (unsigned)f2bf(v.x) | ((unsigned)f2bf(v.y) << 16);
  r.y = (unsigned)f2bf(v.z) | ((unsigned)f2bf(v.w) << 16);
  return r;
}
static __device__ __forceinline__ void gld_lds16(const void* g, void* l) {
  __builtin_amdgcn_global_load_lds(
      (const __attribute__((address_space(1))) unsigned*)g,
      (__attribute__((address_space(3))) unsigned*)l, 16, 0, 0);
}
static __device__ __forceinline__ unsigned lds_addr(const void* p) {
  return (unsigned)(size_t)(const __attribute__((address_space(3))) char*)p;
}

// ---- prep: c2[k] = |codebook[k]|^2, cbh = bf16 codebook ------------------
__global__ __launch_bounds__(256) void vq_prep(const float* __restrict__ cb,
                                               float* __restrict__ c2,
                                               ushort* __restrict__ cbh) {
  int k = blockIdx.x * 4 + (threadIdx.x >> 6);
  int lane = threadIdx.x & 63;
  const float4* p = (const float4*)(cb + (size_t)k * DD + lane * 8);
  float4 a = p[0], b = p[1];
  if (cbh) {
    uint2 pa = f4tobf(a), pb = f4tobf(b);
    *(uint4*)(cbh + (size_t)k * DD + lane * 8) = make_uint4(pa.x, pa.y, pb.x, pb.y);
  }
  float s = a.x*a.x + a.y*a.y + a.z*a.z + a.w*a.w
          + b.x*b.x + b.y*b.y + b.z*b.z + b.w*b.w;
  #pragma unroll
  for (int m = 1; m <= 32; m <<= 1) s += __shfl_xor(s, m);
  if (lane == 0) c2[k] = s;
}

// ---- transpose codebook: cbT[d][k] bf16 ----------------------------------
__global__ __launch_bounds__(256) void vq_tr(const float* __restrict__ cb,
                                             ushort* __restrict__ cbT) {
  __shared__ ushort tile[64][65];
  const int kb = blockIdx.x;           // 64-code block
  const int db = blockIdx.y;           // 64-d block
  const int r = threadIdx.x >> 2;      // 0..63
  const int q = threadIdx.x & 3;       // quarter
  const float* src = cb + (size_t)(kb * 64 + r) * DD + db * 64 + q * 16;
  #pragma unroll
  for (int j = 0; j < 16; ++j) tile[q * 16 + j][r] = f2bf(src[j]);
  __syncthreads();
  ushort* dst = cbT + (size_t)(db * 64 + r) * KKK + kb * 64 + q * 16;
  #pragma unroll
  for (int j = 0; j < 16; ++j) dst[j] = tile[r][q * 16 + j];
}

// ---- main fused kernel ---------------------------------------------------
// cs element layout (linear, no pad): E(c,d) = (c>>2)*2048 + (d>>4)*64 + (c&3)*16 + (d&15)
// Score kmap (d-contraction, A/B consistent): slot(lg,j) -> d = base + lg*8 + j  (one b128/frag)
// Recon kmap_c (code-contraction):            slot(lg,j) -> c = lg*4 + (j&3) + 16*(j>>2)
// C/D map (verified): col = lane&15, row = lg*4 + reg.
template <int STAGE_GLD, int RECON_GLOBAL>
__global__ __launch_bounds__(256, 2) void vq_main(
    const float* __restrict__ sf,     // [B][D][T] f32
    const float* __restrict__ cb,     // [K][D] f32
    const ushort* __restrict__ cbh,   // [K][D] bf16
    const ushort* __restrict__ cbT,   // [D][K] bf16 (RECON_GLOBAL)
    const int*  __restrict__ codes,   // [B][T]
    const int*  __restrict__ lens,    // [B]
    const float* __restrict__ c2,     // [K]
    float* __restrict__ num) {
  __shared__ __align__(128) ushort cs[8][2048];       // 32 KB codebook tile
  __shared__ __align__(16) float sred[NWAVE][32][36]; // 18 KB score partials
  __shared__ __align__(16) ushort wlds[32][40];       // 2.5 KB W frags (slot-ordered)
  __shared__ float alds[32], llds[32];
  __shared__ float z2red[NWAVE][32];
  __shared__ float diffred[32];

  const int bidx = blockIdx.x;
  const int b  = bidx >> 7;                 // 128 blocks per batch
  const int t0 = (bidx & 127) << 5;         // 32 rows per block
  const int len = lens[b];
  int vcount = (len + (ENC_STRIDE - 1)) / ENC_STRIDE;
  vcount = vcount < TT ? vcount : TT;
  if (t0 >= vcount) return;

  const int tid = threadIdx.x;
  const int w  = tid >> 6;
  const int l  = tid & 63;
  const int lg = l >> 4;
  const int ln = l & 15;

  if (tid < 32) diffred[tid] = 0.f;

  // ---- z A-fragments (2 row-tiles x 4 K-steps over this wave's 128-d) ----
  const float* sfb = sf + (size_t)b * DD * TT;
  bf16x8 za[2][4];
  float z2p[2] = {0.f, 0.f};
  #pragma unroll
  for (int rt = 0; rt < 2; ++rt) {
    const int trow = t0 + rt * 16 + ln;
    #pragma unroll
    for (int fi = 0; fi < 4; ++fi) {
      #pragma unroll
      for (int j = 0; j < 8; ++j) {
        int d = w * 128 + fi * 32 + lg * 8 + j;
        float vv = sfb[(size_t)d * TT + trow];
        z2p[rt] += vv * vv;
        za[rt][fi][j] = (short)f2bf(vv);
      }
    }
  }
  #pragma unroll
  for (int rt = 0; rt < 2; ++rt) {
    z2p[rt] += __shfl_xor(z2p[rt], 16);
    z2p[rt] += __shfl_xor(z2p[rt], 32);
  }
  if (l < 16) { z2red[w][ln] = z2p[0]; z2red[w][16 + ln] = z2p[1]; }

  // ---- softmax lane constants (wave w owns rows w*8..w*8+8) --------------
  const int myrow   = w * 8 + (ln & 7);
  const int rowlane = lg * 2 + (ln >> 3);   // 0..7 within row-group
  const int pb      = rowlane * 4;          // wlds slot base
  const int c0      = ((pb >> 3) & 3) * 4 + ((pb >> 2) & 1) * 16;  // code base

  // ---- score B-frag byte offsets into cs ---------------------------------
  const char* csb = (const char*)&cs[0][0];
  const int kb0 = ln >> 2, ka = ln & 3;
  const unsigned sb_lane = (unsigned)(ka << 5) + ((lg >> 1) << 7) + ((lg & 1) << 4)
                         + (unsigned)w * 1024;
  const unsigned sb0 = ((unsigned)kb0 << 12) + sb_lane;   // codes 0..15
  const unsigned sb1 = sb0 + (4u << 12);                  // codes 16..31

  // ---- staging constants --------------------------------------------------
  ushort* cs_lin = &cs[0][0];
  int src_off[8];
  #pragma unroll
  for (int j = 0; j < 8; ++j) {           // invert cs linear layout per 16B chunk
    int t = w * 8 + j;
    int E = t * 512 + l * 8;              // element index of this lane's chunk
    int c = ((E >> 11) << 2) | ((E >> 4) & 3);
    int d = (((E >> 6) & 31) << 4) | (E & 15);
    src_off[j] = c * DD + d;
  }
  const int sk = tid >> 3, sd8 = tid & 7;  // fallback cvt path
  const int skb = sk >> 2, ska = sk & 3;

  auto stage_tile = [&](int kt) {
    if (STAGE_GLD) {
      const ushort* kbase = cbh + (size_t)kt * DD;
      #pragma unroll
      for (int j = 0; j < 8; ++j)
        gld_lds16(kbase + src_off[j], cs_lin + (w * 8 + j) * 512);
    } else {
      const float* crow = cb + (size_t)(kt + sk) * DD;
      #pragma unroll
      for (int dbl = 0; dbl < 4; ++dbl) {
        int dblk = sd8 + dbl * 8;
        const float4* pp = (const float4*)(crow + dblk * 16);
        float4 v0 = pp[0], v1 = pp[1], v2 = pp[2], v3 = pp[3];
        uint2 a0 = f4tobf(v0), a1 = f4tobf(v1), a2 = f4tobf(v2), a3 = f4tobf(v3);
        ushort* dst = &cs[skb][dblk * 64 + ska * 16];
        *(uint4*)(dst)     = make_uint4(a0.x, a0.y, a1.x, a1.y);
        *(uint4*)(dst + 8) = make_uint4(a2.x, a2.y, a3.x, a3.y);
      }
    }
  };

  if (RECON_GLOBAL) stage_tile(0);   // prologue stage; visible at first barrier
  __syncthreads();                   // also covers z2red/diffred

  const float z2tot = z2red[0][myrow] + z2red[1][myrow]
                    + z2red[2][myrow] + z2red[3][myrow];

  float mrow = -1e30f, lrow = 0.f;
  f32x4 acc[2][8];
  #pragma unroll
  for (int rt = 0; rt < 2; ++rt)
    #pragma unroll
    for (int dt = 0; dt < 8; ++dt) acc[rt][dt] = (f32x4){0.f, 0.f, 0.f, 0.f};

  for (int it = 0; it < KKK / KT; ++it) {
    const int kt0 = it * KT;
    if (!RECON_GLOBAL) {             // tr path: cs read in recon -> stage at top
      stage_tile(kt0);
      __syncthreads();
    }
    // ---- scores: partial over this wave's 128-d slice --------------------
    f32x4 sc00 = (f32x4){0,0,0,0}, sc01 = (f32x4){0,0,0,0};
    f32x4 sc10 = (f32x4){0,0,0,0}, sc11 = (f32x4){0,0,0,0};
    #pragma unroll
    for (int fi = 0; fi < 4; ++fi) {
      bf16x8 b0 = *(const bf16x8*)(csb + sb0 + fi * 256);
      bf16x8 b1 = *(const bf16x8*)(csb + sb1 + fi * 256);
      sc00 = __builtin_amdgcn_mfma_f32_16x16x32_bf16(za[0][fi], b0, sc00, 0, 0, 0);
      sc01 = __builtin_amdgcn_mfma_f32_16x16x32_bf16(za[0][fi], b1, sc01, 0, 0, 0);
      sc10 = __builtin_amdgcn_mfma_f32_16x16x32_bf16(za[1][fi], b0, sc10, 0, 0, 0);
      sc11 = __builtin_amdgcn_mfma_f32_16x16x32_bf16(za[1][fi], b1, sc11, 0, 0, 0);
    }
    #pragma unroll
    for (int v = 0; v < 4; ++v) {
      sred[w][lg * 4 + v][ln]           = sc00[v];
      sred[w][lg * 4 + v][16 + ln]      = sc01[v];
      sred[w][16 + lg * 4 + v][ln]      = sc10[v];
      sred[w][16 + lg * 4 + v][16 + ln] = sc11[v];
    }
    __syncthreads();                 // [C] sred ready; cs consumed

    // ---- softmax: lane -> row myrow, codes c0..c0+3 ----------------------
    float4 d4 = {0, 0, 0, 0};
    #pragma unroll
    for (int wv = 0; wv < NWAVE; ++wv) {
      const float4 r = *(const float4*)&sred[wv][myrow][c0];
      d4.x += r.x; d4.y += r.y; d4.z += r.z; d4.w += r.w;
    }
    const float4 c2v = *(const float4*)(c2 + kt0 + c0);
    float s0 = -sqrtf(fmaxf(z2tot + c2v.x - 2.f * d4.x, 1e-12f));
    float s1 = -sqrtf(fmaxf(z2tot + c2v.y - 2.f * d4.y, 1e-12f));
    float s2 = -sqrtf(fmaxf(z2tot + c2v.z - 2.f * d4.z, 1e-12f));
    float s3 = -sqrtf(fmaxf(z2tot + c2v.w - 2.f * d4.w, 1e-12f));
    float tmax = fmaxf(fmaxf(s0, s1), fmaxf(s2, s3));
    tmax = fmaxf(tmax, __shfl_xor(tmax, 8));
    tmax = fmaxf(tmax, __shfl_xor(tmax, 16));
    tmax = fmaxf(tmax, __shfl_xor(tmax, 32));
    const bool defer = (tmax <= mrow + 8.f);     // T13: skip rescale
    const float mnew = defer ? mrow : tmax;
    float e0 = __expf(s0 - mnew), e1 = __expf(s1 - mnew);
    float e2 = __expf(s2 - mnew), e3 = __expf(s3 - mnew);
    float esum = e0 + e1 + e2 + e3;
    esum += __shfl_xor(esum, 8);
    esum += __shfl_xor(esum, 16);
    esum += __shfl_xor(esum, 32);
    const float alpha = defer ? 1.f : __expf(mrow - mnew);
    lrow = lrow * alpha + esum;
    mrow = mnew;
    uint2 pk;
    pk.x = (unsigned)f2bf(e0) | ((unsigned)f2bf(e1) << 16);
    pk.y = (unsigned)f2bf(e2) | ((unsigned)f2bf(e3) << 16);
    *(uint2*)&wlds[myrow][pb] = pk;
    if (rowlane == 0) alds[myrow] = alpha;

    if (RECON_GLOBAL && it + 1 < KKK / KT)
      stage_tile(kt0 + KT);          // overlap staging with softmax/recon
    __syncthreads();                 // [D] wlds/alds ready

    // ---- rescale (usually skipped) + recon -------------------------------
    const float aval = alds[l & 31];
    if (!__all(aval == 1.f)) {
      #pragma unroll
      for (int rt = 0; rt < 2; ++rt)
        #pragma unroll
        for (int v = 0; v < 4; ++v) {
          float av = __shfl(aval, rt * 16 + lg * 4 + v);
          #pragma unroll
          for (int dt = 0; dt < 8; ++dt) acc[rt][dt][v] *= av;
        }
    }
    FragU wa0, wa1;
    wa0.u4 = *(const uint4*)&wlds[ln][lg * 8];
    wa1.u4 = *(const uint4*)&wlds[16 + ln][lg * 8];
    if (RECON_GLOBAL) {
      FragU cf[8];
      #pragma unroll
      for (int dt = 0; dt < 8; ++dt) {
        const ushort* tr_ = cbT + (size_t)(w * 128 + dt * 16 + ln) * KKK + kt0;
        cf[dt].h2[0] = *(const uint2*)(tr_ + lg * 4);
        cf[dt].h2[1] = *(const uint2*)(tr_ + 16 + lg * 4);
      }
      #pragma unroll
      for (int dt = 0; dt < 8; ++dt) {
        acc[0][dt] = __builtin_amdgcn_mfma_f32_16x16x32_bf16(wa0.v, cf[dt].v, acc[0][dt], 0, 0, 0);
        acc[1][dt] = __builtin_amdgcn_mfma_f32_16x16x32_bf16(wa1.v, cf[dt].v, acc[1][dt], 0, 0, 0);
      }
    } else {
      const unsigned tr_base = lds_addr(cs_lin) + (unsigned)(lg * 4096 + w * 1024 + ln * 8);
      unsigned long long tq0[8], tq1[8];
      #pragma unroll
      for (int dt = 0; dt < 8; ++dt) {
        asm volatile("ds_read_b64_tr_b16 %0, %2 offset:%3\n\t"
                     "ds_read_b64_tr_b16 %1, %2 offset:%4"
                     : "=&v"(tq0[dt]), "=&v"(tq1[dt])
                     : "v"(tr_base), "i"(dt * 128), "i"(16384 + dt * 128));
      }
      asm volatile("s_waitcnt lgkmcnt(0)" ::: "memory");
      __builtin_amdgcn_sched_barrier(0);
      #pragma unroll
      for (int dt = 0; dt < 8; ++dt) {
        FragU cf; cf.q[0] = tq0[dt]; cf.q[1] = tq1[dt];
        acc[0][dt] = __builtin_amdgcn_mfma_f32_16x16x32_bf16(wa0.v, cf.v, acc[0][dt], 0, 0, 0);
        acc[1][dt] = __builtin_amdgcn_mfma_f32_16x16x32_bf16(wa1.v, cf.v, acc[1][dt], 0, 0, 0);
      }
    }
    __syncthreads();                 // [A/B] staged cs visible; sred reusable
  }

  // ---- epilogue -----------------------------------------------------------
  if (l < 8) llds[w * 8 + l] = lrow;
  __syncthreads();
  const int* tcodes = codes + b * TT + t0;
  #pragma unroll
  for (int rt = 0; rt < 2; ++rt) {
    float pv[4];
    #pragma unroll
    for (int v = 0; v < 4; ++v) {
      const int row = rt * 16 + lg * 4 + v;
      const float lv = llds[row];
      const int tc = tcodes[row];
      const float* erow = cb + (size_t)tc * DD;
      float psum = 0.f;
      #pragma unroll
      for (int dt = 0; dt < 8; ++dt) {
        int d = w * 128 + dt * 16 + ln;
        float r = acc[rt][dt][v] / lv;
        float df = r - erow[d];
        psum += df * df;
      }
      pv[v] = psum;
    }
    #pragma unroll
    for (int v = 0; v < 4; ++v) {
      pv[v] += __shfl_xor(pv[v], 1);
      pv[v] += __shfl_xor(pv[v], 2);
      pv[v] += __shfl_xor(pv[v], 4);
      pv[v] += __shfl_xor(pv[v], 8);
    }
    if (ln == 0) {
      #pragma unroll
      for (int v = 0; v < 4; ++v)
        atomicAdd(&diffred[rt * 16 + lg * 4 + v], pv[v]);
    }
  }
  __syncthreads();
  if (tid < 32) {
    float val = (t0 + tid < vcount) ? diffred[tid] * (1.f / DD) : 0.f;
    val += __shfl_xor(val, 1);
    val += __shfl_xor(val, 2);
    val += __shfl_xor(val, 4);
    val += __shfl_xor(val, 8);
    val += __shfl_xor(val, 16);
    if (tid == 0) atomicAdd(num, val);
  }
}

// ---- finalize: loss = num / (sum(mask) + 1e-8) ---------------------------
__global__ void vq_finalize(const float* __restrict__ num,
                            const int* __restrict__ lens,
                            float* __restrict__ out) {
  float denom = 0.f;
  for (int b = 0; b < BB; ++b) {
    int v = (lens[b] + (ENC_STRIDE - 1)) / ENC_STRIDE;
    v = v < TT ? v : TT;
    denom += (float)v;
  }
  out[0] = num[0] / (denom + 1e-8f);
}

extern "C" void kernel_launch(void* const* d_in, const int* in_sizes, int n_in,
                              void* d_out, int out_size, void* d_ws, size_t ws_size,
                              hipStream_t stream) {
  const float* sf    = (const float*)d_in[0];
  const float* cb    = (const float*)d_in[1];
  const int*   codes = (const int*)d_in[2];
  const int*   lens  = (const int*)d_in[3];
  float* out = (float*)d_out;
  float* num = (float*)d_ws;                        // [0]: loss numerator
  float* c2  = (float*)((char*)d_ws + 256);         // [4096] f32
  const size_t MB4 = (size_t)KKK * DD * sizeof(ushort);
  ushort* cbh = (ws_size >= 32768 + MB4)     ? (ushort*)((char*)d_ws + 32768) : nullptr;
  ushort* cbT = (ws_size >= 32768 + 2 * MB4) ? (ushort*)((char*)d_ws + 32768 + MB4) : nullptr;

  hipMemsetAsync(d_ws, 0, 4, stream);
  vq_prep<<<KKK / 4, 256, 0, stream>>>(cb, c2, cbh);
  if (cbT) vq_tr<<<dim3(KKK / 64, DD / 64), 256, 0, stream>>>(cb, cbT);
  const int grid = (BB * TT) / 32;
  if (cbh && cbT)
    vq_main<1, 1><<<grid, 256, 0, stream>>>(sf, cb, cbh, cbT, codes, lens, c2, num);
  else if (cbh)
    vq_main<1, 0><<<grid, 256, 0, stream>>>(sf, cb, cbh, cbT, codes, lens, c2, num);
  else
    vq_main<0, 0><<<grid, 256, 0, stream>>>(sf, cb, cbh, cbT, codes, lens, c2, num);
  vq_finalize<<<1, 1, 0, stream>>>(num, lens, out);
}

// Round 4
// 366.794 us; speedup vs baseline: 3.4227x; 3.4227x over previous
//
#include <hip/hip_runtime.h>
#include <hip/hip_bf16.h>

// VQDistortionLoss: fused cdist -> softmax -> soft-recon -> masked MSE.
// R4: latency-oriented rewrite. 128-row blocks (8 waves), 256 blocks = 1/CU,
//     single round (no tail). Swapped score MFMA (A=cb,B=z) -> per-row scores
//     land in-register (sred round-trip deleted). Per-wave d-slice recon.
//     4-buffer LDS pipeline, ONE barrier/ktile; stage(it+2) issued right after
//     the barrier that proves recon(it-2) freed its buffer -> vmcnt drains are
//     always ~1.3k cycles stale. cs kb-padded (+16B) for ~2-way score reads;
//     tr-read strides re-derived from R2's verified mapping.

#define BB 8
#define DD 512
#define TT 4096
#define KKK 4096
#define ENC_STRIDE 320
#define KT 32
#define NKT (KKK / KT)     // 128
#define NW 8               // waves per block
#define ROWS 128           // rows per block
#define KBROW 2056         // ushorts per kb-row (2048 + 8 pad)
#define KBBYTES 4112
#define BUFB (8 * KBBYTES) // 32896 bytes per cs buffer

typedef __attribute__((ext_vector_type(8))) short bf16x8;  // 8 bf16 = 4 VGPR
typedef __attribute__((ext_vector_type(4))) float f32x4;

union FragU { bf16x8 v; uint2 h2[2]; ushort us[8]; unsigned long long q[2]; uint4 u4; };

static __device__ __forceinline__ ushort f2bf(float x) {
  unsigned u = __float_as_uint(x);
  unsigned r = (u + 0x7FFFu + ((u >> 16) & 1u)) >> 16;
  return (ushort)r;
}
static __device__ __forceinline__ uint2 f4tobf(float4 v) {
  uint2 r;
  r.x = (unsigned)f2bf(v.x) | ((unsigned)f2bf(v.y) << 16);
  r.y = (unsigned)f2bf(v.z) | ((unsigned)f2bf(v.w) << 16);
  return r;
}
static __device__ __forceinline__ void gld_lds16(const void* g, void* l) {
  __builtin_amdgcn_global_load_lds(
      (const __attribute__((address_space(1))) unsigned*)g,
      (__attribute__((address_space(3))) unsigned*)l, 16, 0, 0);
}
static __device__ __forceinline__ unsigned lds_addr(const void* p) {
  return (unsigned)(size_t)(const __attribute__((address_space(3))) char*)p;
}

// ---- prep: c2[k] = |codebook[k]|^2 (f32), cbh = bf16 codebook -------------
__global__ __launch_bounds__(256) void vq_prep(const float* __restrict__ cb,
                                               float* __restrict__ c2,
                                               ushort* __restrict__ cbh) {
  int k = blockIdx.x * 4 + (threadIdx.x >> 6);
  int lane = threadIdx.x & 63;
  const float4* p = (const float4*)(cb + (size_t)k * DD + lane * 8);
  float4 a = p[0], b = p[1];
  if (cbh) {
    uint2 pa = f4tobf(a), pb = f4tobf(b);
    *(uint4*)(cbh + (size_t)k * DD + lane * 8) = make_uint4(pa.x, pa.y, pb.x, pb.y);
  }
  float s = a.x*a.x + a.y*a.y + a.z*a.z + a.w*a.w
          + b.x*b.x + b.y*b.y + b.z*b.z + b.w*b.w;
  #pragma unroll
  for (int m = 1; m <= 32; m <<= 1) s += __shfl_xor(s, m);
  if (lane == 0) c2[k] = s;
}

// ---- main fused kernel ----------------------------------------------------
// cs element layout per kb-block (kb = code>>2, padded rows):
//   byte(c,d) = kb*4112 + (d>>4)*128 + (c&3)*32 + (d&15)*2
// Score: A=cb (lane ln<->code, slots d = f*32 + lg*8 + j), B=za (lane<->row).
//   D: col(lane&15)=row, row(lg*4+v)=code  -> scores in-register per row.
// Recon: A=W (lane<->row, slot i<4 -> code lg*4+i, i>=4 -> 16+lg*4+(i-4)),
//   B=cb via ds_read_b64_tr_b16 (same slot map, verified R2), D row = row.
template <int GLD>
__global__ __launch_bounds__(512, 2) void vq_main(
    const float* __restrict__ sf,     // [B][D][T] f32
    const float* __restrict__ cb,     // [K][D] f32
    const ushort* __restrict__ cbh,   // [K][D] bf16 (GLD path)
    const int*  __restrict__ codes,   // [B][T] (int32 low words)
    const int*  __restrict__ lens,    // [B]
    const float* __restrict__ c2,     // [K]
    float* __restrict__ num) {
  __shared__ __align__(128) ushort cs[4][8][KBROW];   // 131584 B
  __shared__ ushort wlds[2][NW][16][36];              // 18432 B
  __shared__ float  alds[2][ROWS];                    // 1024 B
  __shared__ float  llds[ROWS];
  __shared__ float  diffred[ROWS];
  __shared__ int    flagv[NKT];                       // per-ktile rescale flag

  const int bid = blockIdx.x;
  const int b  = bid >> 5;                  // 32 blocks per batch
  const int t0 = (bid & 31) << 7;           // 128 rows per block
  const int len = lens[b];
  int vcount = (len + (ENC_STRIDE - 1)) / ENC_STRIDE;
  vcount = vcount < TT ? vcount : TT;
  if (t0 >= vcount) return;

  const int tid = threadIdx.x;
  const int w  = tid >> 6;
  const int l  = tid & 63;
  const int lg = l >> 4;
  const int ln = l & 15;

  for (int i = tid; i < ROWS; i += 512) diffred[i] = 0.f;
  for (int i = tid; i < NKT; i += 512) flagv[i] = 0;

  // ---- z B-fragments: wave w owns rows t0+w*16 .. +15 (lane ln <-> row) ---
  const float* sfb = sf + (size_t)b * DD * TT;
  const int trow = t0 + w * 16 + ln;
  bf16x8 za[16];
  float z2 = 0.f;
  #pragma unroll
  for (int f = 0; f < 16; ++f) {
    #pragma unroll
    for (int j = 0; j < 8; ++j) {
      int d = f * 32 + lg * 8 + j;
      float v = sfb[(size_t)d * TT + trow];
      z2 += v * v;
      za[f][j] = (short)f2bf(v);
    }
  }
  z2 += __shfl_xor(z2, 16);
  z2 += __shfl_xor(z2, 32);          // full |z|^2 for row ln (all lg agree)

  // ---- staging: wave w stages kb=w of each tile (4 chunks of 1KB) ---------
  // chunk q, lane l covers ushort p = q*512 + l*8 of the kb-row:
  //   code = kt*32 + w*4 + ((l>>1)&3), d = (q*8 + (l>>3))*16 + (l&1)*8
  const int sbase = (w * 4 + ((l >> 1) & 3)) * DD + (l >> 3) * 16 + (l & 1) * 8;

  auto stage = [&](int kt, int buf) {
    if (GLD) {
      const ushort* gb = cbh + (size_t)kt * KT * DD + sbase;
      ushort* lb = &cs[buf][w][0];
      #pragma unroll
      for (int q = 0; q < 4; ++q) gld_lds16(gb + q * 128, lb + q * 512);
    } else {
      const float* gb = cb + (size_t)kt * KT * DD + sbase;
      #pragma unroll
      for (int q = 0; q < 4; ++q) {
        float4 v0 = *(const float4*)(gb + q * 128);
        float4 v1 = *(const float4*)(gb + q * 128 + 4);
        uint2 a0 = f4tobf(v0), a1 = f4tobf(v1);
        *(uint4*)&cs[buf][w][q * 512 + l * 8] = make_uint4(a0.x, a0.y, a1.x, a1.y);
      }
    }
  };

  stage(0, 0); stage(1, 1); stage(2, 2);   // prologue: 3 tiles in flight

  float mrow = -1e30f, lrow = 0.f;
  f32x4 acc[8][4];
  #pragma unroll
  for (int r = 0; r < 8; ++r)
    #pragma unroll
    for (int nt = 0; nt < 4; ++nt) acc[r][nt] = (f32x4){0.f, 0.f, 0.f, 0.f};

  const unsigned score_lane = (unsigned)((ln >> 2) * KBBYTES + (ln & 3) * 32
                                         + (lg >> 1) * 128 + (lg & 1) * 16);
  const unsigned tr_lane = (unsigned)(lg * KBBYTES + w * 512 + ln * 8);
  const unsigned cs0a = lds_addr(&cs[0][0][0]);

  // ---- scores(it) + softmax(it): fully wave-local -------------------------
  auto scores_softmax = [&](int it, int sbuf) {
    const char* csb = (const char*)&cs[sbuf][0][0];
    f32x4 sc0 = (f32x4){0,0,0,0}, sc1 = (f32x4){0,0,0,0};
    #pragma unroll
    for (int f = 0; f < 16; ++f) {
      bf16x8 a0 = *(const bf16x8*)(csb + score_lane + f * 256);
      bf16x8 a1 = *(const bf16x8*)(csb + score_lane + 16448 + f * 256);
      sc0 = __builtin_amdgcn_mfma_f32_16x16x32_bf16(a0, za[f], sc0, 0, 0, 0);
      sc1 = __builtin_amdgcn_mfma_f32_16x16x32_bf16(a1, za[f], sc1, 0, 0, 0);
    }
    const float4 c2a = *(const float4*)(c2 + it * KT + lg * 4);
    const float4 c2b = *(const float4*)(c2 + it * KT + 16 + lg * 4);
    float sv[8];
    float c2v[8] = {c2a.x, c2a.y, c2a.z, c2a.w, c2b.x, c2b.y, c2b.z, c2b.w};
    #pragma unroll
    for (int v = 0; v < 4; ++v) {
      sv[v]     = -sqrtf(fmaxf(z2 + c2v[v]     - 2.f * sc0[v], 1e-12f));
      sv[4 + v] = -sqrtf(fmaxf(z2 + c2v[4 + v] - 2.f * sc1[v], 1e-12f));
    }
    float tmax = sv[0];
    #pragma unroll
    for (int i = 1; i < 8; ++i) tmax = fmaxf(tmax, sv[i]);
    tmax = fmaxf(tmax, __shfl_xor(tmax, 16));
    tmax = fmaxf(tmax, __shfl_xor(tmax, 32));   // row-max (per ln)
    const bool defer = (tmax <= mrow + 8.f);    // T13
    const float mnew = defer ? mrow : tmax;
    float e[8], esum = 0.f;
    #pragma unroll
    for (int i = 0; i < 8; ++i) { e[i] = __expf(sv[i] - mnew); esum += e[i]; }
    esum += __shfl_xor(esum, 16);
    esum += __shfl_xor(esum, 32);
    const float alpha = defer ? 1.f : __expf(mrow - mnew);
    lrow = lrow * alpha + esum;
    mrow = mnew;
    const int s = it & 1;
    uint2 lopk, hipk;
    lopk.x = (unsigned)f2bf(e[0]) | ((unsigned)f2bf(e[1]) << 16);
    lopk.y = (unsigned)f2bf(e[2]) | ((unsigned)f2bf(e[3]) << 16);
    hipk.x = (unsigned)f2bf(e[4]) | ((unsigned)f2bf(e[5]) << 16);
    hipk.y = (unsigned)f2bf(e[6]) | ((unsigned)f2bf(e[7]) << 16);
    *(uint2*)&wlds[s][w][ln][lg * 4]      = lopk;   // codes lg*4+0..3
    *(uint2*)&wlds[s][w][ln][16 + lg * 4] = hipk;   // codes 16+lg*4+0..3
    if (lg == 0) alds[s][w * 16 + ln] = alpha;
    if (!__all(defer) && l == 0) flagv[it] = 1;     // benign multi-wave store
  };

  // ---- recon(itm1): acc += W(itm1) x C(tile itm1) over wave's 64-d slice --
  auto recon = [&](int itm1) {
    const int s = itm1 & 1;
    const int rb = itm1 & 3;
    const unsigned trb = cs0a + (unsigned)rb * BUFB + tr_lane;
    unsigned long long tq0[4], tq1[4];
    #pragma unroll
    for (int nt = 0; nt < 4; ++nt) {
      asm volatile("ds_read_b64_tr_b16 %0, %2 offset:%3\n\t"
                   "ds_read_b64_tr_b16 %1, %2 offset:%4"
                   : "=&v"(tq0[nt]), "=&v"(tq1[nt])
                   : "v"(trb), "i"(nt * 128), "i"(16448 + nt * 128));
    }
    asm volatile("s_waitcnt lgkmcnt(0)" ::: "memory");
    __builtin_amdgcn_sched_barrier(0);
    FragU cf[4];
    #pragma unroll
    for (int nt = 0; nt < 4; ++nt) { cf[nt].q[0] = tq0[nt]; cf[nt].q[1] = tq1[nt]; }
    if (flagv[itm1]) {                 // rare: rescale acc rows by alpha
      #pragma unroll
      for (int r = 0; r < 8; ++r)
        #pragma unroll
        for (int v = 0; v < 4; ++v) {
          float av = alds[s][r * 16 + lg * 4 + v];
          #pragma unroll
          for (int nt = 0; nt < 4; ++nt) acc[r][nt][v] *= av;
        }
    }
    #pragma unroll
    for (int rh = 0; rh < 2; ++rh) {
      FragU wa[4];
      #pragma unroll
      for (int r4 = 0; r4 < 4; ++r4) {
        wa[r4].h2[0] = *(const uint2*)&wlds[s][rh * 4 + r4][ln][lg * 4];
        wa[r4].h2[1] = *(const uint2*)&wlds[s][rh * 4 + r4][ln][16 + lg * 4];
      }
      #pragma unroll
      for (int r4 = 0; r4 < 4; ++r4)
        #pragma unroll
        for (int nt = 0; nt < 4; ++nt)
          acc[rh * 4 + r4][nt] = __builtin_amdgcn_mfma_f32_16x16x32_bf16(
              wa[r4].v, cf[nt].v, acc[rh * 4 + r4][nt], 0, 0, 0);
    }
  };

  __syncthreads();                 // prologue: staged tiles drained, LDS init
  scores_softmax(0, 0);

  #pragma unroll 1
  for (int it = 1; it < NKT; ++it) {
    __syncthreads();               // ONE barrier/ktile: W(it-1)+alds visible;
                                   // recon(it-2) done by all -> buf (it+2)&3 free;
                                   // stage(it+1) (issued last body) drained.
    if (it + 2 < NKT) stage(it + 2, (it + 2) & 3);
    recon(it - 1);
    scores_softmax(it, it & 3);
  }
  __syncthreads();                 // W(127) visible
  recon(NKT - 1);

  // ---- epilogue -----------------------------------------------------------
  if (lg == 0) llds[w * 16 + ln] = lrow;
  __syncthreads();
  const int* tcodes = codes + b * TT + t0;
  #pragma unroll
  for (int r = 0; r < 8; ++r) {
    float pv[4];
    #pragma unroll
    for (int v = 0; v < 4; ++v) {
      const int row = r * 16 + lg * 4 + v;
      const float lv = llds[row];
      const int tc = tcodes[row];
      const float* erow = cb + (size_t)tc * DD + w * 64;
      float ps = 0.f;
      #pragma unroll
      for (int nt = 0; nt < 4; ++nt) {
        float rc = acc[r][nt][v] / lv;
        float df = rc - erow[nt * 16 + ln];
        ps += df * df;
      }
      pv[v] = ps;
    }
    #pragma unroll
    for (int v = 0; v < 4; ++v) {
      pv[v] += __shfl_xor(pv[v], 1);
      pv[v] += __shfl_xor(pv[v], 2);
      pv[v] += __shfl_xor(pv[v], 4);
      pv[v] += __shfl_xor(pv[v], 8);
    }
    if (ln == 0) {
      #pragma unroll
      for (int v = 0; v < 4; ++v)
        atomicAdd(&diffred[r * 16 + lg * 4 + v], pv[v]);
    }
  }
  __syncthreads();
  if (tid < ROWS) {
    float val = (t0 + tid < vcount) ? diffred[tid] * (1.f / DD) : 0.f;
    val += __shfl_xor(val, 1);
    val += __shfl_xor(val, 2);
    val += __shfl_xor(val, 4);
    val += __shfl_xor(val, 8);
    val += __shfl_xor(val, 16);
    val += __shfl_xor(val, 32);
    if ((tid & 63) == 0) atomicAdd(num, val);
  }
}

// ---- finalize: loss = num / (sum(mask) + 1e-8) ---------------------------
__global__ void vq_finalize(const float* __restrict__ num,
                            const int* __restrict__ lens,
                            float* __restrict__ out) {
  float denom = 0.f;
  for (int b = 0; b < BB; ++b) {
    int v = (lens[b] + (ENC_STRIDE - 1)) / ENC_STRIDE;
    v = v < TT ? v : TT;
    denom += (float)v;
  }
  out[0] = num[0] / (denom + 1e-8f);
}

extern "C" void kernel_launch(void* const* d_in, const int* in_sizes, int n_in,
                              void* d_out, int out_size, void* d_ws, size_t ws_size,
                              hipStream_t stream) {
  const float* sf    = (const float*)d_in[0];
  const float* cb    = (const float*)d_in[1];
  const int*   codes = (const int*)d_in[2];
  const int*   lens  = (const int*)d_in[3];
  float* out = (float*)d_out;
  float* num = (float*)d_ws;                        // [0]: loss numerator
  float* c2  = (float*)((char*)d_ws + 256);         // [4096] f32
  const size_t need = 32768 + (size_t)KKK * DD * sizeof(ushort);
  ushort* cbh = (ws_size >= need) ? (ushort*)((char*)d_ws + 32768) : nullptr;

  hipMemsetAsync(d_ws, 0, 4, stream);
  vq_prep<<<KKK / 4, 256, 0, stream>>>(cb, c2, cbh);
  const int grid = (BB * TT) / ROWS;                // 256 blocks, 512 threads
  if (cbh)
    vq_main<1><<<grid, 512, 0, stream>>>(sf, cb, cbh, codes, lens, c2, num);
  else
    vq_main<0><<<grid, 512, 0, stream>>>(sf, cb, cbh, codes, lens, c2, num);
  vq_finalize<<<1, 1, 0, stream>>>(num, lens, out);
}